// Round 4
// baseline (137.909 us; speedup 1.0000x reference)
//
#include <hip/hip_runtime.h>
#include <math.h>

// Capsule dynamic routing, fused, G=2 batches per block to halve L2 W-traffic.
// One block of 512 threads per (c, batch-pair). B=256, C=10, N=1152, Din=8,
// U=16, 3 routing iterations.
// Thread t owns u = (t&3)*4..+3, n = (t>>2) + 128k, k=0..8, for BOTH batches:
// u_hat = 18 named float4 registers (arrays spilled in rounds 1-2).
// Each W float4 is loaded once and used for both batches' FMAs.
// x is loaded directly from global (quad-duplicate lanes merge at the
// coalescer; x stays L2/L3 resident) -> LDS ~10.5 KB, no x staging.
// __launch_bounds__(512,1): no occupancy-floor VGPR cap (rounds 1-2 showed
// a cap below the live set causes GB-scale scratch thrash).

#define BATCH 256
#define CAPS  10
#define NIN   1152
#define DIN   8
#define UDIM  16
#define TPB   512
#define NBLK  ((BATCH / 2) * CAPS)   // 1280

__global__ __launch_bounds__(TPB, 1) void capsule_routing_kernel(
    const float* __restrict__ x,   // (B, N, Din)
    const float* __restrict__ W,   // (C, N, Din, U)
    float* __restrict__ out)       // (B, C, U)
{
    // XCD-aware swizzle: dispatch is ~round-robin over 8 XCDs by blockIdx;
    // make blocks resident on one XCD share c so W[c] chunks stay in its L2.
    const int blk = blockIdx.x;
    const int grp = blk >> 3;           // 0..159
    const int l8  = blk & 7;            // XCD lane
    const int c   = grp >> 4;           // 0..9   (16 consecutive groups per c)
    const int j   = grp & 15;           // 0..15
    const int bp  = (j << 3) | l8;      // 0..127 batch pair
    const int b0  = bp << 1;            // even batch; b1 = b0+1

    const int t    = threadIdx.x;       // 0..511
    const int ub   = (t & 3) << 2;      // u base: 0,4,8,12
    const int gg   = t >> 2;            // 0..127 (n residue)
    const int wave = t >> 6;            // 0..7

    __shared__ float b_s[2][NIN];                       // routing logits
    __shared__ float redB[2][8];                        // per-wave exp sums
    __shared__ __align__(16) float ps[2][8][UDIM];      // per-wave partial s
    __shared__ __align__(16) float v_s[2][UDIM];        // squashed outputs

    for (int n = t; n < NIN; n += TPB) { b_s[0][n] = 1.0f; b_s[1][n] = 1.0f; }
    __syncthreads();

    const float4* xp0 = (const float4*)(x + (size_t)b0 * (NIN * DIN) + gg * DIN);
    const float4* xp1 = (const float4*)(x + (size_t)(b0 + 1) * (NIN * DIN) + gg * DIN);
    const float4* wp  = (const float4*)(W + (size_t)c * (NIN * DIN * UDIM)
                                          + gg * (DIN * UDIM) + ub);

    // ---- u_hat: 2 batches x 9 groups of named float4 registers ----
    float4 u00, u01, u02, u03, u04, u05, u06, u07, u08;
    float4 u10, u11, u12, u13, u14, u15, u16, u17, u18;

// One k-group: n = gg + 128*K. Two din-halves fenced by sched_barrier to
// bound peak live registers (~116) under the 4-waves/SIMD cliff at 128.
#define UHK(D0, D1) { \
    const float4 xa0 = xp0[0]; \
    const float4 xa1 = xp1[0]; \
    { float4 w0 = wp[0], w1 = wp[4], w2 = wp[8], w3 = wp[12]; \
      D0.x = xa0.x*w0.x + xa0.y*w1.x + xa0.z*w2.x + xa0.w*w3.x; \
      D0.y = xa0.x*w0.y + xa0.y*w1.y + xa0.z*w2.y + xa0.w*w3.y; \
      D0.z = xa0.x*w0.z + xa0.y*w1.z + xa0.z*w2.z + xa0.w*w3.z; \
      D0.w = xa0.x*w0.w + xa0.y*w1.w + xa0.z*w2.w + xa0.w*w3.w; \
      D1.x = xa1.x*w0.x + xa1.y*w1.x + xa1.z*w2.x + xa1.w*w3.x; \
      D1.y = xa1.x*w0.y + xa1.y*w1.y + xa1.z*w2.y + xa1.w*w3.y; \
      D1.z = xa1.x*w0.z + xa1.y*w1.z + xa1.z*w2.z + xa1.w*w3.z; \
      D1.w = xa1.x*w0.w + xa1.y*w1.w + xa1.z*w2.w + xa1.w*w3.w; } \
    __builtin_amdgcn_sched_barrier(0); \
    { const float4 xb0 = xp0[1]; \
      const float4 xb1 = xp1[1]; \
      float4 w0 = wp[16], w1 = wp[20], w2 = wp[24], w3 = wp[28]; \
      D0.x += xb0.x*w0.x + xb0.y*w1.x + xb0.z*w2.x + xb0.w*w3.x; \
      D0.y += xb0.x*w0.y + xb0.y*w1.y + xb0.z*w2.y + xb0.w*w3.y; \
      D0.z += xb0.x*w0.z + xb0.y*w1.z + xb0.z*w2.z + xb0.w*w3.z; \
      D0.w += xb0.x*w0.w + xb0.y*w1.w + xb0.z*w2.w + xb0.w*w3.w; \
      D1.x += xb1.x*w0.x + xb1.y*w1.x + xb1.z*w2.x + xb1.w*w3.x; \
      D1.y += xb1.x*w0.y + xb1.y*w1.y + xb1.z*w2.y + xb1.w*w3.y; \
      D1.z += xb1.x*w0.z + xb1.y*w1.z + xb1.z*w2.z + xb1.w*w3.z; \
      D1.w += xb1.x*w0.w + xb1.y*w1.w + xb1.z*w2.w + xb1.w*w3.w; } \
    xp0 += 256; xp1 += 256; wp += 4096; \
    __builtin_amdgcn_sched_barrier(0); }

    UHK(u00, u10) UHK(u01, u11) UHK(u02, u12)
    UHK(u03, u13) UHK(u04, u14) UHK(u05, u15)
    UHK(u06, u16) UHK(u07, u17) UHK(u08, u18)

    // ---- 3 routing iterations ----
    for (int it = 0; it < 3; ++it) {
        // e = exp(b), no max-shift (b stays in ~[0.2, 1.9]; softmax is
        // shift-invariant). Each n's exp computed by its 4 owner threads ->
        // denominator partials 4x overcounted, divided out later.
        float le0 = 0.f, le1 = 0.f;
        float4 p0; p0.x = p0.y = p0.z = p0.w = 0.f;
        float4 p1; p1.x = p1.y = p1.z = p1.w = 0.f;

#define ACCP(K, U0, U1) { \
        const float e0 = __expf(b_s[0][gg + 128 * (K)]); \
        const float e1 = __expf(b_s[1][gg + 128 * (K)]); \
        le0 += e0; le1 += e1; \
        p0.x += e0 * U0.x; p0.y += e0 * U0.y; \
        p0.z += e0 * U0.z; p0.w += e0 * U0.w; \
        p1.x += e1 * U1.x; p1.y += e1 * U1.y; \
        p1.z += e1 * U1.z; p1.w += e1 * U1.w; }

        ACCP(0, u00, u10) ACCP(1, u01, u11) ACCP(2, u02, u12)
        ACCP(3, u03, u13) ACCP(4, u04, u14) ACCP(5, u05, u15)
        ACCP(6, u06, u16) ACCP(7, u07, u17) ACCP(8, u08, u18)

        #pragma unroll
        for (int mk = 1; mk <= 32; mk <<= 1) {
            le0 += __shfl_xor(le0, mk);
            le1 += __shfl_xor(le1, mk);
        }
        if ((t & 63) == 0) { redB[0][wave] = le0; redB[1][wave] = le1; }

        #pragma unroll
        for (int mk = 4; mk <= 32; mk <<= 1) {
            p0.x += __shfl_xor(p0.x, mk); p0.y += __shfl_xor(p0.y, mk);
            p0.z += __shfl_xor(p0.z, mk); p0.w += __shfl_xor(p0.w, mk);
            p1.x += __shfl_xor(p1.x, mk); p1.y += __shfl_xor(p1.y, mk);
            p1.z += __shfl_xor(p1.z, mk); p1.w += __shfl_xor(p1.w, mk);
        }
        if ((t & 63) < 4) {   // lanes 0..3: wave sums for ub = (t&3)*4
            ps[0][wave][ub + 0] = p0.x; ps[0][wave][ub + 1] = p0.y;
            ps[0][wave][ub + 2] = p0.z; ps[0][wave][ub + 3] = p0.w;
            ps[1][wave][ub + 0] = p1.x; ps[1][wave][ub + 1] = p1.y;
            ps[1][wave][ub + 2] = p1.z; ps[1][wave][ub + 3] = p1.w;
        }
        __syncthreads();

        // squash: threads 0..31 handle (g = t>>4, u = t&15)
        if (t < 32) {
            const int g = t >> 4, u = t & 15;
            float esum = 0.f, s = 0.f;
            #pragma unroll
            for (int w = 0; w < 8; ++w) { esum += redB[g][w]; s += ps[g][w][u]; }
            s *= 4.0f / esum;              // 4x overcount of denominator
            float sq = s * s;
            #pragma unroll
            for (int mk = 1; mk <= 8; mk <<= 1) sq += __shfl_xor(sq, mk);
            const float scale = sq / ((1.0f + sq) * sqrtf(sq + 1e-9f));
            const float v = scale * s;
            v_s[g][u] = v;
            if (it == 2) out[((size_t)(b0 + g) * CAPS + c) * UDIM + u] = v;
        }
        __syncthreads();

        // b[n] += u_hat[n] . v
        if (it < 2) {
            const float4 v40 = *(const float4*)(&v_s[0][ub]);
            const float4 v41 = *(const float4*)(&v_s[1][ub]);

#define BUPD(K, U0, U1) { \
            float q0 = U0.x*v40.x + U0.y*v40.y + U0.z*v40.z + U0.w*v40.w; \
            float q1 = U1.x*v41.x + U1.y*v41.y + U1.z*v41.z + U1.w*v41.w; \
            q0 += __shfl_xor(q0, 1); q0 += __shfl_xor(q0, 2); \
            q1 += __shfl_xor(q1, 1); q1 += __shfl_xor(q1, 2); \
            if ((t & 3) == 0) { \
                b_s[0][gg + 128 * (K)] += q0; \
                b_s[1][gg + 128 * (K)] += q1; } }

            BUPD(0, u00, u10) BUPD(1, u01, u11) BUPD(2, u02, u12)
            BUPD(3, u03, u13) BUPD(4, u04, u14) BUPD(5, u05, u15)
            BUPD(6, u06, u16) BUPD(7, u07, u17) BUPD(8, u08, u18)
            __syncthreads();
        }
    }
}

extern "C" void kernel_launch(void* const* d_in, const int* in_sizes, int n_in,
                              void* d_out, int out_size, void* d_ws, size_t ws_size,
                              hipStream_t stream) {
    const float* x = (const float*)d_in[0];   // (256, 1152, 8)
    const float* W = (const float*)d_in[1];   // (10, 1152, 8, 16)
    float* out = (float*)d_out;               // (256, 10, 16)
    capsule_routing_kernel<<<NBLK, TPB, 0, stream>>>(x, W, out);
}

// Round 5
// 133.097 us; speedup vs baseline: 1.0362x; 1.0362x over previous
//
#include <hip/hip_runtime.h>
#include <math.h>

// Capsule dynamic routing, fully fused: one block of 512 threads per (b, c).
// B=256, C=10, N=1152, Din=8, U=16, 3 routing iterations.
//
// Round-4 lesson: kernel is LATENCY-bound (HBM 4%, VALU<40%, L2 far from
// saturated). Occupancy is the lever. This round:
//  - G=1 (round-4's G=2 halved occupancy -> slower)
//  - NO x LDS staging: x read directly from global (quad-duplicate lanes
//    merge at the coalescer; x is L2/L3-resident). LDS 42.5KB -> ~5.3KB,
//    so blocks/CU: 3 (LDS-limited) -> 4 (wave-slot-limited, 100% ceiling).
//  - iteration 0 softmax skipped: b is uniform -> c = 1/N exactly, and by
//    shift-invariance b_s needs no "1.0" init (BUPD stores on it=0).
//  - u_hat in NINE NAMED float4 regs (arrays spilled in rounds 1-2);
//    sched_barrier fences hold peak live regs near 64 (8-wave/SIMD cliff).
//  - __launch_bounds__(512,1): no occupancy-floor VGPR cap (rounds 1-2:
//    a cap below the live set causes GB-scale scratch thrash).

#define BATCH 256
#define CAPS  10
#define NIN   1152
#define DIN   8
#define UDIM  16
#define TPB   512

__global__ __launch_bounds__(TPB, 1) void capsule_routing_kernel(
    const float* __restrict__ x,   // (B, N, Din)
    const float* __restrict__ W,   // (C, N, Din, U)
    float* __restrict__ out)       // (B, C, U)
{
    const int blk = blockIdx.x;       // c-major for L2 W-locality
    const int c   = blk >> 8;         // 0..9
    const int b   = blk & 255;        // 0..255
    const int t    = threadIdx.x;     // 0..511
    const int ub   = (t & 3) << 2;    // u base: 0,4,8,12
    const int gg   = t >> 2;          // 0..127 (n residue)
    const int wave = t >> 6;          // 0..7

    __shared__ float b_s[NIN];                    // routing logits (4.6 KB)
    __shared__ float redB[8];                     // per-wave exp sums
    __shared__ __align__(16) float ps[8][UDIM];   // per-wave partial s
    __shared__ __align__(16) float v_s[UDIM];     // squashed output vector

    const float4* xp = (const float4*)(x + (size_t)b * (NIN * DIN) + gg * DIN);
    const float4* wp = (const float4*)(W + (size_t)c * (NIN * DIN * UDIM)
                                         + gg * (DIN * UDIM) + ub);

    // ---- u_hat: 9 named float4 registers; n = gg + 128k ----
    float4 uh0, uh1, uh2, uh3, uh4, uh5, uh6, uh7, uh8;

// Two din-halves fenced by sched_barrier to bound peak live registers.
#define UHK(DST) { \
    float4 acc; \
    { const float4 xa = xp[0]; \
      float4 w0 = wp[0], w1 = wp[4], w2 = wp[8], w3 = wp[12]; \
      acc.x = xa.x*w0.x + xa.y*w1.x + xa.z*w2.x + xa.w*w3.x; \
      acc.y = xa.x*w0.y + xa.y*w1.y + xa.z*w2.y + xa.w*w3.y; \
      acc.z = xa.x*w0.z + xa.y*w1.z + xa.z*w2.z + xa.w*w3.z; \
      acc.w = xa.x*w0.w + xa.y*w1.w + xa.z*w2.w + xa.w*w3.w; } \
    __builtin_amdgcn_sched_barrier(0); \
    { const float4 xb = xp[1]; \
      float4 w0 = wp[16], w1 = wp[20], w2 = wp[24], w3 = wp[28]; \
      acc.x += xb.x*w0.x + xb.y*w1.x + xb.z*w2.x + xb.w*w3.x; \
      acc.y += xb.x*w0.y + xb.y*w1.y + xb.z*w2.y + xb.w*w3.y; \
      acc.z += xb.x*w0.z + xb.y*w1.z + xb.z*w2.z + xb.w*w3.z; \
      acc.w += xb.x*w0.w + xb.y*w1.w + xb.z*w2.w + xb.w*w3.w; } \
    xp += 256; wp += 4096; \
    DST = acc; \
    __builtin_amdgcn_sched_barrier(0); }

    UHK(uh0) UHK(uh1) UHK(uh2)
    UHK(uh3) UHK(uh4) UHK(uh5)
    UHK(uh6) UHK(uh7) UHK(uh8)

    // ================= iteration 0: softmax of uniform b is exactly 1/N ===
    {
        float4 p;
        p.x = uh0.x + uh1.x + uh2.x + uh3.x + uh4.x + uh5.x + uh6.x + uh7.x + uh8.x;
        p.y = uh0.y + uh1.y + uh2.y + uh3.y + uh4.y + uh5.y + uh6.y + uh7.y + uh8.y;
        p.z = uh0.z + uh1.z + uh2.z + uh3.z + uh4.z + uh5.z + uh6.z + uh7.z + uh8.z;
        p.w = uh0.w + uh1.w + uh2.w + uh3.w + uh4.w + uh5.w + uh6.w + uh7.w + uh8.w;
        #pragma unroll
        for (int mk = 4; mk <= 32; mk <<= 1) {
            p.x += __shfl_xor(p.x, mk); p.y += __shfl_xor(p.y, mk);
            p.z += __shfl_xor(p.z, mk); p.w += __shfl_xor(p.w, mk);
        }
        if ((t & 63) < 4) {
            ps[wave][ub + 0] = p.x; ps[wave][ub + 1] = p.y;
            ps[wave][ub + 2] = p.z; ps[wave][ub + 3] = p.w;
        }
        __syncthreads();
        if (t < UDIM) {
            float s = 0.f;
            #pragma unroll
            for (int w = 0; w < 8; ++w) s += ps[w][t];
            s *= (1.0f / (float)NIN);
            float sq = s * s;
            #pragma unroll
            for (int mk = 1; mk <= 8; mk <<= 1) sq += __shfl_xor(sq, mk);
            const float scale = sq / ((1.0f + sq) * sqrtf(sq + 1e-9f));
            v_s[t] = scale * s;
        }
        __syncthreads();
        // b_s = u_hat . v  (shift-invariant: the reference's "+1" drops out)
        const float4 v4 = *(const float4*)(v_s + ub);
#define BST(K, UH) { \
        float q = UH.x*v4.x + UH.y*v4.y + UH.z*v4.z + UH.w*v4.w; \
        q += __shfl_xor(q, 1); q += __shfl_xor(q, 2); \
        if ((t & 3) == 0) b_s[gg + 128 * (K)] = q; }
        BST(0, uh0) BST(1, uh1) BST(2, uh2)
        BST(3, uh3) BST(4, uh4) BST(5, uh5)
        BST(6, uh6) BST(7, uh7) BST(8, uh8)
        __syncthreads();
    }

    // ================= iterations 1, 2 ====================================
    for (int it = 1; it < 3; ++it) {
        // e = exp(b); each n's exp computed by its 4 owner threads, so the
        // denominator partials are 4x overcounted -> divide by 4 later.
        float le = 0.f;
        float4 p; p.x = p.y = p.z = p.w = 0.f;
#define ACCP(K, UH) { \
        const float e = __expf(b_s[gg + 128 * (K)]); \
        le += e; \
        p.x += e * UH.x; p.y += e * UH.y; p.z += e * UH.z; p.w += e * UH.w; }
        ACCP(0, uh0) ACCP(1, uh1) ACCP(2, uh2)
        ACCP(3, uh3) ACCP(4, uh4) ACCP(5, uh5)
        ACCP(6, uh6) ACCP(7, uh7) ACCP(8, uh8)

        #pragma unroll
        for (int mk = 1; mk <= 32; mk <<= 1) le += __shfl_xor(le, mk);
        if ((t & 63) == 0) redB[wave] = le;

        #pragma unroll
        for (int mk = 4; mk <= 32; mk <<= 1) {
            p.x += __shfl_xor(p.x, mk); p.y += __shfl_xor(p.y, mk);
            p.z += __shfl_xor(p.z, mk); p.w += __shfl_xor(p.w, mk);
        }
        if ((t & 63) < 4) {
            ps[wave][ub + 0] = p.x; ps[wave][ub + 1] = p.y;
            ps[wave][ub + 2] = p.z; ps[wave][ub + 3] = p.w;
        }
        __syncthreads();

        if (t < UDIM) {
            float esum = 0.f, s = 0.f;
            #pragma unroll
            for (int w = 0; w < 8; ++w) { esum += redB[w]; s += ps[w][t]; }
            s *= 4.0f / esum;              // 4x overcount of denominator
            float sq = s * s;
            #pragma unroll
            for (int mk = 1; mk <= 8; mk <<= 1) sq += __shfl_xor(sq, mk);
            const float scale = sq / ((1.0f + sq) * sqrtf(sq + 1e-9f));
            const float v = scale * s;
            v_s[t] = v;
            if (it == 2) out[((size_t)b * CAPS + c) * UDIM + t] = v;
        }
        __syncthreads();

        if (it == 1) {
            const float4 v4 = *(const float4*)(v_s + ub);
#define BADD(K, UH) { \
            float q = UH.x*v4.x + UH.y*v4.y + UH.z*v4.z + UH.w*v4.w; \
            q += __shfl_xor(q, 1); q += __shfl_xor(q, 2); \
            if ((t & 3) == 0) b_s[gg + 128 * (K)] += q; }
            BADD(0, uh0) BADD(1, uh1) BADD(2, uh2)
            BADD(3, uh3) BADD(4, uh4) BADD(5, uh5)
            BADD(6, uh6) BADD(7, uh7) BADD(8, uh8)
            __syncthreads();
        }
    }
}

extern "C" void kernel_launch(void* const* d_in, const int* in_sizes, int n_in,
                              void* d_out, int out_size, void* d_ws, size_t ws_size,
                              hipStream_t stream) {
    const float* x = (const float*)d_in[0];   // (256, 1152, 8)
    const float* W = (const float*)d_in[1];   // (10, 1152, 8, 16)
    float* out = (float*)d_out;               // (256, 10, 16)
    capsule_routing_kernel<<<BATCH * CAPS, TPB, 0, stream>>>(x, W, out);
}